// Round 2
// baseline (498.454 us; speedup 1.0000x reference)
//
#include <hip/hip_runtime.h>
#include <hip/hip_bf16.h>

#define SS 256
#define BB 512
#define II 64
#define HH 128
#define DD 32

typedef __attribute__((ext_vector_type(8))) short short8;   // 8 bf16 (4 VGPRs)
typedef __attribute__((ext_vector_type(4))) float f32x4;

__device__ __forceinline__ short f2bf(float f) {
    unsigned u = __builtin_bit_cast(unsigned, f);
    u += 0x7FFFu + ((u >> 16) & 1u);            // RNE
    return (short)(u >> 16);
}
__device__ __forceinline__ int pack2bf(float a, float b) {
    return (int)((((unsigned)(unsigned short)f2bf(b)) << 16) |
                  ((unsigned)(unsigned short)f2bf(a)));
}
__device__ __forceinline__ short8 load8bf(const float* p) {
    short8 r;
#pragma unroll
    for (int j = 0; j < 8; ++j) r[j] = f2bf(p[j]);
    return r;
}

// barrier with LDS-only drain: global stores/prefetches stay in flight
__device__ __forceinline__ void sync_lds() {
    __builtin_amdgcn_s_waitcnt(0xc07f);   // lgkmcnt(0); vmcnt/expcnt = max
    __builtin_amdgcn_s_barrier();
}

// ---------------------------------------------------------------------------
// K1: masked per-channel sum/sumsq for BOTH x (C=64) and x_d (C=32) in one
// launch. blocks [0,256) -> x, [256,384) -> x_d.
// acc layout: [0:64]=sum_x [64:128]=sq_x [128:160]=sum_d [160:192]=sq_d
// ---------------------------------------------------------------------------
__global__ __launch_bounds__(256) void stats_kernel(
    const float* __restrict__ x, const float* __restrict__ xd,
    const int* __restrict__ lengths, double* __restrict__ acc)
{
    __shared__ float red_s[256];
    __shared__ float red_q[256];
    const int rows = SS * BB;
    int blk = blockIdx.x;
    const float* v;
    int C, rpb, base;
    if (blk < 256) { v = x;  C = II; rpb = rows / 256; base = 0; }
    else           { v = xd; C = DD; rpb = rows / 128; base = 128; blk -= 256; }

    const int tid = threadIdx.x;
    const int c   = tid & (C - 1);
    const int rg  = tid / C;
    const int rpg = 256 / C;
    const int r0  = blk * rpb;
    const int r1  = r0 + rpb;
    float s = 0.f, q = 0.f;
    for (int r = r0 + rg; r < r1; r += rpg) {
        const int b  = r & (BB - 1);
        const int si = r >> 9;
        if (si < lengths[b]) {
            const float xv = v[(size_t)r * C + c];
            s += xv;
            q  = fmaf(xv, xv, q);
        }
    }
    red_s[tid] = s; red_q[tid] = q;
    __syncthreads();
    if (rg == 0) {
        for (int g = 1; g < rpg; ++g) { s += red_s[c + g * C]; q += red_q[c + g * C]; }
        atomicAdd(&acc[base + c],     (double)s);
        atomicAdd(&acc[base + C + c], (double)q);
    }
}

// ---------------------------------------------------------------------------
// K2: finalize -> folded BN coefficients  xn = x*a + c
// der layout: [0:64]=a_x [64:128]=c_x [128:160]=a_d [160:192]=c_d
// ---------------------------------------------------------------------------
__global__ __launch_bounds__(128) void finalize_kernel(
    const int* __restrict__ lengths, const double* __restrict__ acc,
    const float* __restrict__ bn_g, const float* __restrict__ bn_b,
    const float* __restrict__ bnd_g, const float* __restrict__ bnd_b,
    float* __restrict__ der)
{
    __shared__ int redc[128];
    __shared__ double s_inv;
    const int tid = threadIdx.x;
    int cs = 0;
    for (int i = tid; i < BB; i += 128) cs += lengths[i];
    redc[tid] = cs;
    __syncthreads();
    if (tid == 0) {
        int tot = 0;
        for (int i = 0; i < 128; ++i) tot += redc[i];
        s_inv = 1.0 / (double)tot;
    }
    __syncthreads();
    const double inv = s_inv;
    if (tid < 64) {
        const double mu  = acc[tid] * inv;
        const double var = acc[64 + tid] * inv - mu * mu;
        const float  rs  = rsqrtf((float)(var + 1e-5));
        const float  a   = rs * bn_g[tid];
        der[tid]      = a;
        der[64 + tid] = bn_b[tid] - (float)mu * a;
    } else if (tid < 96) {
        const int i = tid - 64;
        const double mu  = acc[128 + i] * inv;
        const double var = acc[160 + i] * inv - mu * mu;
        const float  rs  = rsqrtf((float)(var + 1e-5));
        const float  a   = rs * bnd_g[i];
        der[128 + i] = a;
        der[160 + i] = bnd_b[i] - (float)mu * a;
    }
}

// ---------------------------------------------------------------------------
// K3: GRU only. 32 blocks x 256 threads (4 waves); block = 16 batch rows.
// 4-wave layout: each wave owns 32 hidden units (two 16-row A-frag sets per
// gate, 36 MFMAs/step), so each Hf fragment feeds 6 MFMAs and the per-step
// LDS B-operand read volume is HALVED vs the 8-wave version (24KB vs 48KB).
// Per-SIMD issue work is unchanged (1 wave doing 2x); ILP inside the wave
// doubles (8 independent unit chains/lane). __launch_bounds__(256,1) gives
// the full 512-reg budget (~280 live regs: 36 weight frags + 8 accs).
// ONE lgkm-only barrier per step; ys stores and x prefetches never drained.
// ---------------------------------------------------------------------------
__global__ __launch_bounds__(256, 1) void gru_kernel(
    const float* __restrict__ x, const int* __restrict__ lengths,
    const float* __restrict__ Wih, const float* __restrict__ Whh,
    const float* __restrict__ bih, const float* __restrict__ bhh,
    const float* __restrict__ der,
    float* __restrict__ ys, float* __restrict__ hlast)
{
    __shared__ __align__(16) short hbf[2][16 * 136];
    __shared__ __align__(16) short xbf[2][16 * 72];

    const int tid  = threadIdx.x;         // 0..255
    const int w    = tid >> 6;            // wave 0..3
    const int l    = tid & 63;
    const int col  = l & 15;              // token (batch row within block)
    const int quad = l >> 4;
    const int b0   = blockIdx.x * 16;
    const int ur0  = 32 * w + col;        // weight row, A-frag set 0
    const int ur1  = ur0 + 16;            // weight row, A-frag set 1
    const int g0   = 32 * w + quad * 4;   // first output unit, set 0
    const int g1   = g0 + 16;             // first output unit, set 1

    short8 WR0[6], WZ0[6], WNh0[4], WNx0[2];
    short8 WR1[6], WZ1[6], WNh1[4], WNx1[2];
#pragma unroll
    for (int ks = 0; ks < 4; ++ks) {
        const int ko = ks * 32 + quad * 8;
        WR0[ks]  = load8bf(&Whh[(size_t)ur0 * HH + ko]);
        WR1[ks]  = load8bf(&Whh[(size_t)ur1 * HH + ko]);
        WZ0[ks]  = load8bf(&Whh[(size_t)(HH + ur0) * HH + ko]);
        WZ1[ks]  = load8bf(&Whh[(size_t)(HH + ur1) * HH + ko]);
        WNh0[ks] = load8bf(&Whh[(size_t)(2 * HH + ur0) * HH + ko]);
        WNh1[ks] = load8bf(&Whh[(size_t)(2 * HH + ur1) * HH + ko]);
    }
#pragma unroll
    for (int ks = 0; ks < 2; ++ks) {
        const int ko = ks * 32 + quad * 8;
        WR0[4 + ks] = load8bf(&Wih[(size_t)ur0 * II + ko]);
        WR1[4 + ks] = load8bf(&Wih[(size_t)ur1 * II + ko]);
        WZ0[4 + ks] = load8bf(&Wih[(size_t)(HH + ur0) * II + ko]);
        WZ1[4 + ks] = load8bf(&Wih[(size_t)(HH + ur1) * II + ko]);
        WNx0[ks]    = load8bf(&Wih[(size_t)(2 * HH + ur0) * II + ko]);
        WNx1[ks]    = load8bf(&Wih[(size_t)(2 * HH + ur1) * II + ko]);
    }
    float br0_[4], bz0_[4], bnh0_[4], bnx0_[4];
    float br1_[4], bz1_[4], bnh1_[4], bnx1_[4];
#pragma unroll
    for (int r = 0; r < 4; ++r) {
        int g = g0 + r;
        br0_[r]  = bih[g] + bhh[g];
        bz0_[r]  = bih[HH + g] + bhh[HH + g];
        bnh0_[r] = bhh[2 * HH + g];
        bnx0_[r] = bih[2 * HH + g];
        g = g1 + r;
        br1_[r]  = bih[g] + bhh[g];
        bz1_[r]  = bih[HH + g] + bhh[HH + g];
        bnh1_[r] = bhh[2 * HH + g];
        bnx1_[r] = bih[2 * HH + g];
    }
    const int len = lengths[b0 + col];

    // x staging: all 256 threads, one float4 each (16 rows x 64 cols)
    const int srow = tid >> 4, scol = (tid & 15) * 4;
    float axc[4], cxc[4];
#pragma unroll
    for (int j = 0; j < 4; ++j) {
        axc[j] = der[scol + j];
        cxc[j] = der[64 + scol + j];
    }

    for (int i = tid; i < 16 * 136 / 2; i += 256) ((int*)hbf[0])[i] = 0;
    float hreg0[4] = {0.f, 0.f, 0.f, 0.f};
    float hreg1[4] = {0.f, 0.f, 0.f, 0.f};
    {
        const float4 xv = *(const float4*)&x[(size_t)(b0 + srow) * II + scol];
        int2 pk;
        pk.x = pack2bf(fmaf(xv.x, axc[0], cxc[0]), fmaf(xv.y, axc[1], cxc[1]));
        pk.y = pack2bf(fmaf(xv.z, axc[2], cxc[2]), fmaf(xv.w, axc[3], cxc[3]));
        *(int2*)&xbf[0][srow * 72 + scol] = pk;
    }
    sync_lds();

    int p = 0;
    for (int t = 0; t < SS; ++t) {
        float4 xv;
        if (t + 1 < SS)
            xv = *(const float4*)&x[(size_t)((t + 1) * BB + b0 + srow) * II + scol];

        short8 Hf[4];
#pragma unroll
        for (int ks = 0; ks < 4; ++ks)
            Hf[ks] = *(const short8*)&hbf[p][col * 136 + ks * 32 + quad * 8];
        const short8 XN0 = *(const short8*)&xbf[p][col * 72 + quad * 8];
        const short8 XN1 = *(const short8*)&xbf[p][col * 72 + 32 + quad * 8];

        f32x4 ar0  = {br0_[0],  br0_[1],  br0_[2],  br0_[3]};
        f32x4 ar1  = {br1_[0],  br1_[1],  br1_[2],  br1_[3]};
        f32x4 az0  = {bz0_[0],  bz0_[1],  bz0_[2],  bz0_[3]};
        f32x4 az1  = {bz1_[0],  bz1_[1],  bz1_[2],  bz1_[3]};
        f32x4 anh0 = {bnh0_[0], bnh0_[1], bnh0_[2], bnh0_[3]};
        f32x4 anh1 = {bnh1_[0], bnh1_[1], bnh1_[2], bnh1_[3]};
        f32x4 anx0 = {bnx0_[0], bnx0_[1], bnx0_[2], bnx0_[3]};
        f32x4 anx1 = {bnx1_[0], bnx1_[1], bnx1_[2], bnx1_[3]};
#pragma unroll
        for (int ks = 0; ks < 4; ++ks) {
            ar0  = __builtin_amdgcn_mfma_f32_16x16x32_bf16(WR0[ks],  Hf[ks], ar0,  0, 0, 0);
            ar1  = __builtin_amdgcn_mfma_f32_16x16x32_bf16(WR1[ks],  Hf[ks], ar1,  0, 0, 0);
            az0  = __builtin_amdgcn_mfma_f32_16x16x32_bf16(WZ0[ks],  Hf[ks], az0,  0, 0, 0);
            az1  = __builtin_amdgcn_mfma_f32_16x16x32_bf16(WZ1[ks],  Hf[ks], az1,  0, 0, 0);
            anh0 = __builtin_amdgcn_mfma_f32_16x16x32_bf16(WNh0[ks], Hf[ks], anh0, 0, 0, 0);
            anh1 = __builtin_amdgcn_mfma_f32_16x16x32_bf16(WNh1[ks], Hf[ks], anh1, 0, 0, 0);
        }
        ar0  = __builtin_amdgcn_mfma_f32_16x16x32_bf16(WR0[4],  XN0, ar0,  0, 0, 0);
        ar0  = __builtin_amdgcn_mfma_f32_16x16x32_bf16(WR0[5],  XN1, ar0,  0, 0, 0);
        ar1  = __builtin_amdgcn_mfma_f32_16x16x32_bf16(WR1[4],  XN0, ar1,  0, 0, 0);
        ar1  = __builtin_amdgcn_mfma_f32_16x16x32_bf16(WR1[5],  XN1, ar1,  0, 0, 0);
        az0  = __builtin_amdgcn_mfma_f32_16x16x32_bf16(WZ0[4],  XN0, az0,  0, 0, 0);
        az0  = __builtin_amdgcn_mfma_f32_16x16x32_bf16(WZ0[5],  XN1, az0,  0, 0, 0);
        az1  = __builtin_amdgcn_mfma_f32_16x16x32_bf16(WZ1[4],  XN0, az1,  0, 0, 0);
        az1  = __builtin_amdgcn_mfma_f32_16x16x32_bf16(WZ1[5],  XN1, az1,  0, 0, 0);
        anx0 = __builtin_amdgcn_mfma_f32_16x16x32_bf16(WNx0[0], XN0, anx0, 0, 0, 0);
        anx0 = __builtin_amdgcn_mfma_f32_16x16x32_bf16(WNx0[1], XN1, anx0, 0, 0, 0);
        anx1 = __builtin_amdgcn_mfma_f32_16x16x32_bf16(WNx1[0], XN0, anx1, 0, 0, 0);
        anx1 = __builtin_amdgcn_mfma_f32_16x16x32_bf16(WNx1[1], XN1, anx1, 0, 0, 0);

        const bool valid = (t < len);
#pragma unroll
        for (int r = 0; r < 4; ++r) {
            {
                const float rg = __builtin_amdgcn_rcpf(1.f + __expf(-ar0[r]));
                const float zg = __builtin_amdgcn_rcpf(1.f + __expf(-az0[r]));
                const float nv = anx0[r] + rg * anh0[r];
                const float ng = 1.f - 2.f * __builtin_amdgcn_rcpf(1.f + __expf(2.f * nv));
                const float hnew = (1.f - zg) * ng + zg * hreg0[r];
                hreg0[r] = valid ? hnew : hreg0[r];
            }
            {
                const float rg = __builtin_amdgcn_rcpf(1.f + __expf(-ar1[r]));
                const float zg = __builtin_amdgcn_rcpf(1.f + __expf(-az1[r]));
                const float nv = anx1[r] + rg * anh1[r];
                const float ng = 1.f - 2.f * __builtin_amdgcn_rcpf(1.f + __expf(2.f * nv));
                const float hnew = (1.f - zg) * ng + zg * hreg1[r];
                hreg1[r] = valid ? hnew : hreg1[r];
            }
        }
        {   // ys stores (drain-free) + bf16 h for next step
            float4 o0, o1;
            o0.x = hreg0[0]; o0.y = hreg0[1]; o0.z = hreg0[2]; o0.w = hreg0[3];
            o1.x = hreg1[0]; o1.y = hreg1[1]; o1.z = hreg1[2]; o1.w = hreg1[3];
            const size_t yb = ((size_t)t * BB + b0 + col) * HH;
            *(float4*)&ys[yb + g0] = o0;
            *(float4*)&ys[yb + g1] = o1;
            int2 pk0, pk1;
            pk0.x = pack2bf(hreg0[0], hreg0[1]);
            pk0.y = pack2bf(hreg0[2], hreg0[3]);
            pk1.x = pack2bf(hreg1[0], hreg1[1]);
            pk1.y = pack2bf(hreg1[2], hreg1[3]);
            *(int2*)&hbf[p ^ 1][col * 136 + g0] = pk0;
            *(int2*)&hbf[p ^ 1][col * 136 + g1] = pk1;
        }
        if (t + 1 < SS) {
            int2 pk;
            pk.x = pack2bf(fmaf(xv.x, axc[0], cxc[0]), fmaf(xv.y, axc[1], cxc[1]));
            pk.y = pack2bf(fmaf(xv.z, axc[2], cxc[2]), fmaf(xv.w, axc[3], cxc[3]));
            *(int2*)&xbf[p ^ 1][srow * 72 + scol] = pk;
        }

        sync_lds();
        p ^= 1;
    }

    {
        float4 hl0, hl1;
        hl0.x = hreg0[0]; hl0.y = hreg0[1]; hl0.z = hreg0[2]; hl0.w = hreg0[3];
        hl1.x = hreg1[0]; hl1.y = hreg1[1]; hl1.z = hreg1[2]; hl1.w = hreg1[3];
        const size_t hb = (size_t)(b0 + col) * HH;
        *(float4*)&hlast[hb + g0] = hl0;
        *(float4*)&hlast[hb + g1] = hl1;
    }
}

// ---------------------------------------------------------------------------
// K4: 3-layer MLP, in-place on d_out. 512 blocks x 512 threads; 16 tiles of
// 16 tokens per block, 3-stage pipeline (L1 tile i / L2 i-1 / L3 i-2) with
// ONE lgkm-only barrier per step; next tile's y/xd prefetched in registers.
// Weights VGPR-resident (13 frags = 52 VGPR).
// ---------------------------------------------------------------------------
__global__ __launch_bounds__(512, 2) void mlp_kernel(
    const float* __restrict__ xd, const int* __restrict__ lengths,
    const float* __restrict__ W1, const float* __restrict__ b1v,
    const float* __restrict__ W2, const float* __restrict__ b2v,
    const float* __restrict__ W3, const float* __restrict__ b3v,
    const float* __restrict__ der, float* io)
{
    __shared__ __align__(16) short z0[2][16 * 168];
    __shared__ __align__(16) short d1b[2][16 * 136];
    __shared__ __align__(16) short d2b[2][16 * 136];

    const int tid  = threadIdx.x;
    const int w    = tid >> 6;
    const int l    = tid & 63;
    const int col  = l & 15;
    const int quad = l >> 4;
    const int ur   = 16 * w + col;
    const int g0   = 16 * w + quad * 4;

    short8 F1[5], F2[4], F3[4];
#pragma unroll
    for (int ks = 0; ks < 5; ++ks)
        F1[ks] = load8bf(&W1[(size_t)ur * 160 + ks * 32 + quad * 8]);
#pragma unroll
    for (int ks = 0; ks < 4; ++ks) {
        const int ko = ks * 32 + quad * 8;
        F2[ks] = load8bf(&W2[(size_t)ur * HH + ko]);
        F3[ks] = load8bf(&W3[(size_t)ur * HH + ko]);
    }
    float bb1_[4], bb2_[4], bb3_[4];
#pragma unroll
    for (int r = 0; r < 4; ++r) {
        bb1_[r] = b1v[g0 + r]; bb2_[r] = b2v[g0 + r]; bb3_[r] = b3v[g0 + r];
    }

    // staging maps: y = 512 thr x float4 (16x128); xd = 256 thr x float2 (16x32)
    const int yrow = tid >> 5, yc = (tid & 31) * 4;
    const int drow = tid >> 4, dcol = (tid & 15) * 2;
    float ad0 = 0.f, ad1 = 0.f, cd0 = 0.f, cd1 = 0.f;
    if (tid < 256) {
        ad0 = der[128 + dcol]; ad1 = der[128 + dcol + 1];
        cd0 = der[160 + dcol]; cd1 = der[160 + dcol + 1];
    }

    const int tile0 = blockIdx.x * 16;

    {   // pre-stage tile 0
        const size_t tok0 = (size_t)tile0 * 16;
        const float4 yv = *(const float4*)&io[(tok0 + yrow) * HH + yc];
        int2 pk;
        pk.x = pack2bf(yv.x, yv.y);
        pk.y = pack2bf(yv.z, yv.w);
        *(int2*)&z0[0][yrow * 168 + yc] = pk;
        if (tid < 256) {
            const float2 dv = *(const float2*)&xd[(tok0 + drow) * DD + dcol];
            *(int*)&z0[0][drow * 168 + HH + dcol] =
                pack2bf(fmaf(dv.x, ad0, cd0), fmaf(dv.y, ad1, cd1));
        }
    }
    sync_lds();

    int p = 0;
    for (int it = 0; it <= 17; ++it) {
        // prefetch tile it+1 into registers
        float4 yv; float2 dv;
        const int nt = it + 1;
        if (nt <= 15) {
            const size_t tok0n = (size_t)(tile0 + nt) * 16;
            yv = *(const float4*)&io[(tok0n + yrow) * HH + yc];
            if (tid < 256) dv = *(const float2*)&xd[(tok0n + drow) * DD + dcol];
        }

        // L1 (tile it): z0[p] -> d1b[p^1]
        f32x4 a1 = {bb1_[0], bb1_[1], bb1_[2], bb1_[3]};
#pragma unroll
        for (int ks = 0; ks < 5; ++ks)
            a1 = __builtin_amdgcn_mfma_f32_16x16x32_bf16(
                F1[ks], *(const short8*)&z0[p][col * 168 + ks * 32 + quad * 8], a1, 0, 0, 0);
        {
            int2 pk;
            pk.x = pack2bf(fmaxf(a1[0], 0.f), fmaxf(a1[1], 0.f));
            pk.y = pack2bf(fmaxf(a1[2], 0.f), fmaxf(a1[3], 0.f));
            *(int2*)&d1b[p ^ 1][col * 136 + g0] = pk;
        }

        // L2 (tile it-1): d1b[p] -> d2b[p^1]
        f32x4 a2 = {bb2_[0], bb2_[1], bb2_[2], bb2_[3]};
#pragma unroll
        for (int ks = 0; ks < 4; ++ks)
            a2 = __builtin_amdgcn_mfma_f32_16x16x32_bf16(
                F2[ks], *(const short8*)&d1b[p][col * 136 + ks * 32 + quad * 8], a2, 0, 0, 0);
        {
            int2 pk;
            pk.x = pack2bf(fmaxf(a2[0], 0.f), fmaxf(a2[1], 0.f));
            pk.y = pack2bf(fmaxf(a2[2], 0.f), fmaxf(a2[3], 0.f));
            *(int2*)&d2b[p ^ 1][col * 136 + g0] = pk;
        }

        // L3 (tile it-2): d2b[p] -> out (drain-free store)
        f32x4 a3 = {bb3_[0], bb3_[1], bb3_[2], bb3_[3]};
#pragma unroll
        for (int ks = 0; ks < 4; ++ks)
            a3 = __builtin_amdgcn_mfma_f32_16x16x32_bf16(
                F3[ks], *(const short8*)&d2b[p][col * 136 + ks * 32 + quad * 8], a3, 0, 0, 0);
        if (it >= 2) {
            const int tok0 = (tile0 + it - 2) * 16;
            const int tI = tok0 >> 9;
            const int bI = tok0 & (BB - 1);
            const bool v = tI < lengths[bI + col];
            float4 o;
            o.x = v ? fmaxf(a3[0], 0.f) : 0.f;
            o.y = v ? fmaxf(a3[1], 0.f) : 0.f;
            o.z = v ? fmaxf(a3[2], 0.f) : 0.f;
            o.w = v ? fmaxf(a3[3], 0.f) : 0.f;
            *(float4*)&io[((size_t)tok0 + col) * HH + g0] = o;
        }

        // commit prefetched tile it+1 to z0[p^1]
        if (nt <= 15) {
            int2 pk;
            pk.x = pack2bf(yv.x, yv.y);
            pk.y = pack2bf(yv.z, yv.w);
            *(int2*)&z0[p ^ 1][yrow * 168 + yc] = pk;
            if (tid < 256)
                *(int*)&z0[p ^ 1][drow * 168 + HH + dcol] =
                    pack2bf(fmaf(dv.x, ad0, cd0), fmaf(dv.y, ad1, cd1));
        }
        sync_lds();
        p ^= 1;
    }
}

// ---------------------------------------------------------------------------
extern "C" void kernel_launch(void* const* d_in, const int* in_sizes, int n_in,
                              void* d_out, int out_size, void* d_ws, size_t ws_size,
                              hipStream_t stream)
{
    (void)in_sizes; (void)n_in; (void)out_size; (void)ws_size;
    const float* x     = (const float*)d_in[0];
    const float* xd    = (const float*)d_in[1];
    const int*   lens  = (const int*)d_in[2];
    const float* bn_g  = (const float*)d_in[3];
    const float* bn_b  = (const float*)d_in[4];
    const float* bnd_g = (const float*)d_in[5];
    const float* bnd_b = (const float*)d_in[6];
    const float* Wih   = (const float*)d_in[7];
    const float* Whh   = (const float*)d_in[8];
    const float* bih   = (const float*)d_in[9];
    const float* bhh   = (const float*)d_in[10];
    // d_in[11], d_in[12]: attn_W, attn_b — softmax over size-1 axis == identity
    const float* W1    = (const float*)d_in[13];
    const float* b1    = (const float*)d_in[14];
    const float* W2    = (const float*)d_in[15];
    const float* b2    = (const float*)d_in[16];
    const float* W3    = (const float*)d_in[17];
    const float* b3    = (const float*)d_in[18];

    float* out   = (float*)d_out;
    float* hlast = out + (size_t)SS * BB * HH;

    double* acc = (double*)d_ws;                       // 192 doubles
    float*  der = (float*)((char*)d_ws + 2048);        // 192 floats

    (void)hipMemsetAsync(d_ws, 0, 2048, stream);

    stats_kernel<<<384, 256, 0, stream>>>(x, xd, lens, acc);
    finalize_kernel<<<1, 128, 0, stream>>>(lens, acc, bn_g, bn_b, bnd_g, bnd_b, der);

    gru_kernel<<<BB / 16, 256, 0, stream>>>(x, lens, Wih, Whh, bih, bhh, der,
                                            out, hlast);

    mlp_kernel<<<512, 512, 0, stream>>>(xd, lens, W1, b1, W2, b2, W3, b3,
                                        der, out);
}

// Round 3
// 478.929 us; speedup vs baseline: 1.0408x; 1.0408x over previous
//
#include <hip/hip_runtime.h>
#include <hip/hip_bf16.h>

#define SS 256
#define BB 512
#define II 64
#define HH 128
#define DD 32

typedef __attribute__((ext_vector_type(8))) short short8;   // 8 bf16 (4 VGPRs)
typedef __attribute__((ext_vector_type(4))) float f32x4;

__device__ __forceinline__ short f2bf(float f) {
    unsigned u = __builtin_bit_cast(unsigned, f);
    u += 0x7FFFu + ((u >> 16) & 1u);            // RNE
    return (short)(u >> 16);
}
__device__ __forceinline__ int pack2bf(float a, float b) {
    return (int)((((unsigned)(unsigned short)f2bf(b)) << 16) |
                  ((unsigned)(unsigned short)f2bf(a)));
}
__device__ __forceinline__ short8 load8bf(const float* p) {
    short8 r;
#pragma unroll
    for (int j = 0; j < 8; ++j) r[j] = f2bf(p[j]);
    return r;
}

// barrier with LDS-only drain: global stores/prefetches stay in flight
__device__ __forceinline__ void sync_lds() {
    __builtin_amdgcn_s_waitcnt(0xc07f);   // lgkmcnt(0); vmcnt/expcnt = max
    __builtin_amdgcn_s_barrier();
}

// ---------------------------------------------------------------------------
// K1: masked per-channel sum/sumsq for BOTH x (C=64) and x_d (C=32) in one
// launch, WITH the finalize folded in via last-block ticket (saves a launch).
// blocks [0,256) -> x, [256,384) -> x_d.
// acc layout: [0:64]=sum_x [64:128]=sq_x [128:160]=sum_d [160:192]=sq_d
// counter at ws+1536 (zeroed by the memset each replay).
// der layout: [0:64]=a_x [64:128]=c_x [128:160]=a_d [160:192]=c_d
// ---------------------------------------------------------------------------
__global__ __launch_bounds__(256) void stats_kernel(
    const float* __restrict__ x, const float* __restrict__ xd,
    const int* __restrict__ lengths, double* __restrict__ acc,
    unsigned* __restrict__ counter,
    const float* __restrict__ bn_g, const float* __restrict__ bn_b,
    const float* __restrict__ bnd_g, const float* __restrict__ bnd_b,
    float* __restrict__ der)
{
    __shared__ float red_s[256];
    __shared__ float red_q[256];
    __shared__ unsigned s_last;
    const int rows = SS * BB;
    int blk = blockIdx.x;
    const float* v;
    int C, rpb, base;
    if (blk < 256) { v = x;  C = II; rpb = rows / 256; base = 0; }
    else           { v = xd; C = DD; rpb = rows / 128; base = 128; blk -= 256; }

    const int tid = threadIdx.x;
    const int c   = tid & (C - 1);
    const int rg  = tid / C;
    const int rpg = 256 / C;
    const int r0  = blk * rpb;
    const int r1  = r0 + rpb;
    float s = 0.f, q = 0.f;
    for (int r = r0 + rg; r < r1; r += rpg) {
        const int b  = r & (BB - 1);
        const int si = r >> 9;
        if (si < lengths[b]) {
            const float xv = v[(size_t)r * C + c];
            s += xv;
            q  = fmaf(xv, xv, q);
        }
    }
    red_s[tid] = s; red_q[tid] = q;
    __syncthreads();
    if (rg == 0) {
        for (int g = 1; g < rpg; ++g) { s += red_s[c + g * C]; q += red_q[c + g * C]; }
        atomicAdd(&acc[base + c],     (double)s);
        atomicAdd(&acc[base + C + c], (double)q);
    }
    // ----- last-block ticket: the 384th arriving block finalizes -----
    __threadfence();              // my atomics globally complete before ticket
    __syncthreads();
    if (tid == 0) {
        unsigned old = atomicAdd(counter, 1u);
        s_last = (old == 383u) ? 1u : 0u;
    }
    __syncthreads();
    if (!s_last) return;

    // finalize (runs in exactly one block, after all acc atomics are visible)
    __shared__ int redc[256];
    int cs = 0;
    for (int i = tid; i < BB; i += 256) cs += lengths[i];
    redc[tid] = cs;
    __syncthreads();
    for (int off = 128; off; off >>= 1) {
        if (tid < off) redc[tid] += redc[tid + off];
        __syncthreads();
    }
    const double inv = 1.0 / (double)redc[0];
    if (tid < 64) {
        const double su = __hip_atomic_load(&acc[tid],      __ATOMIC_RELAXED, __HIP_MEMORY_SCOPE_AGENT);
        const double sq = __hip_atomic_load(&acc[64 + tid], __ATOMIC_RELAXED, __HIP_MEMORY_SCOPE_AGENT);
        const double mu  = su * inv;
        const double var = sq * inv - mu * mu;
        const float  rs  = rsqrtf((float)(var + 1e-5));
        const float  a   = rs * bn_g[tid];
        der[tid]      = a;
        der[64 + tid] = bn_b[tid] - (float)mu * a;
    } else if (tid < 96) {
        const int i = tid - 64;
        const double su = __hip_atomic_load(&acc[128 + i], __ATOMIC_RELAXED, __HIP_MEMORY_SCOPE_AGENT);
        const double sq = __hip_atomic_load(&acc[160 + i], __ATOMIC_RELAXED, __HIP_MEMORY_SCOPE_AGENT);
        const double mu  = su * inv;
        const double var = sq * inv - mu * mu;
        const float  rs  = rsqrtf((float)(var + 1e-5));
        const float  a   = rs * bnd_g[i];
        der[128 + i] = a;
        der[160 + i] = bnd_b[i] - (float)mu * a;
    }
}

// ---------------------------------------------------------------------------
// K3: GRU only. 32 blocks x 512 threads; block = 16 batch rows.
// Transposed MFMA: D = W_frag (A) x act_frag (B); lane owns 4 consecutive
// units x 1 token -> float4 ys stores, int2 h writes. Weights VGPR-resident
// (18 frags = 72 VGPR). ONE lgkm-only barrier per step; ys stores and x
// prefetches never drained inside the loop. ys carries hreg even for invalid
// tokens (the MLP's final mask makes those values irrelevant).
// [A/B verdict r2: 4-wave variant regressed 218->242us despite halved LDS
//  traffic — loop is latency-bound; 2 waves/SIMD TLP is load-bearing.]
// ---------------------------------------------------------------------------
__global__ __launch_bounds__(512, 2) void gru_kernel(
    const float* __restrict__ x, const int* __restrict__ lengths,
    const float* __restrict__ Wih, const float* __restrict__ Whh,
    const float* __restrict__ bih, const float* __restrict__ bhh,
    const float* __restrict__ der,
    float* __restrict__ ys, float* __restrict__ hlast)
{
    __shared__ __align__(16) short hbf[2][16 * 136];
    __shared__ __align__(16) short xbf[2][16 * 72];

    const int tid  = threadIdx.x;
    const int w    = tid >> 6;
    const int l    = tid & 63;
    const int col  = l & 15;       // token (batch row within block)
    const int quad = l >> 4;
    const int b0   = blockIdx.x * 16;
    const int ur   = 16 * w + col;        // weight row for A-frags
    const int g0   = 16 * w + quad * 4;   // first output unit of this lane

    short8 WR[6], WZ[6], WNh[4], WNx[2];
#pragma unroll
    for (int ks = 0; ks < 4; ++ks) {
        const int ko = ks * 32 + quad * 8;
        WR[ks]  = load8bf(&Whh[(size_t)ur * HH + ko]);
        WZ[ks]  = load8bf(&Whh[(size_t)(HH + ur) * HH + ko]);
        WNh[ks] = load8bf(&Whh[(size_t)(2 * HH + ur) * HH + ko]);
    }
#pragma unroll
    for (int ks = 0; ks < 2; ++ks) {
        const int ko = ks * 32 + quad * 8;
        WR[4 + ks] = load8bf(&Wih[(size_t)ur * II + ko]);
        WZ[4 + ks] = load8bf(&Wih[(size_t)(HH + ur) * II + ko]);
        WNx[ks]    = load8bf(&Wih[(size_t)(2 * HH + ur) * II + ko]);
    }
    float br_[4], bz_[4], bnh_[4], bnx_[4];
#pragma unroll
    for (int r = 0; r < 4; ++r) {
        const int g = g0 + r;
        br_[r]  = bih[g] + bhh[g];
        bz_[r]  = bih[HH + g] + bhh[HH + g];
        bnh_[r] = bhh[2 * HH + g];
        bnx_[r] = bih[2 * HH + g];
    }
    const int len = lengths[b0 + col];

    // x staging: all 512 threads, one float2 each (16 rows x 64 cols)
    const int srow = tid >> 5, scol = (tid & 31) * 2;
    const float ax0 = der[scol],      ax1 = der[scol + 1];
    const float cx0 = der[64 + scol], cx1 = der[64 + scol + 1];

    for (int i = tid; i < 16 * 136 / 2; i += 512) ((int*)hbf[0])[i] = 0;
    float hreg[4] = {0.f, 0.f, 0.f, 0.f};
    {
        const float2 xv = *(const float2*)&x[(size_t)(b0 + srow) * II + scol];
        *(int*)&xbf[0][srow * 72 + scol] =
            pack2bf(fmaf(xv.x, ax0, cx0), fmaf(xv.y, ax1, cx1));
    }
    sync_lds();

    int p = 0;
    for (int t = 0; t < SS; ++t) {
        float2 xv;
        if (t + 1 < SS)
            xv = *(const float2*)&x[(size_t)((t + 1) * BB + b0 + srow) * II + scol];

        short8 Hf[4];
#pragma unroll
        for (int ks = 0; ks < 4; ++ks)
            Hf[ks] = *(const short8*)&hbf[p][col * 136 + ks * 32 + quad * 8];
        const short8 XN0 = *(const short8*)&xbf[p][col * 72 + quad * 8];
        const short8 XN1 = *(const short8*)&xbf[p][col * 72 + 32 + quad * 8];

        f32x4 ar  = {br_[0],  br_[1],  br_[2],  br_[3]};
        f32x4 az  = {bz_[0],  bz_[1],  bz_[2],  bz_[3]};
        f32x4 anh = {bnh_[0], bnh_[1], bnh_[2], bnh_[3]};
        f32x4 anx = {bnx_[0], bnx_[1], bnx_[2], bnx_[3]};
#pragma unroll
        for (int ks = 0; ks < 4; ++ks) {
            ar  = __builtin_amdgcn_mfma_f32_16x16x32_bf16(WR[ks],  Hf[ks], ar,  0, 0, 0);
            az  = __builtin_amdgcn_mfma_f32_16x16x32_bf16(WZ[ks],  Hf[ks], az,  0, 0, 0);
            anh = __builtin_amdgcn_mfma_f32_16x16x32_bf16(WNh[ks], Hf[ks], anh, 0, 0, 0);
        }
        ar  = __builtin_amdgcn_mfma_f32_16x16x32_bf16(WR[4],  XN0, ar,  0, 0, 0);
        ar  = __builtin_amdgcn_mfma_f32_16x16x32_bf16(WR[5],  XN1, ar,  0, 0, 0);
        az  = __builtin_amdgcn_mfma_f32_16x16x32_bf16(WZ[4],  XN0, az,  0, 0, 0);
        az  = __builtin_amdgcn_mfma_f32_16x16x32_bf16(WZ[5],  XN1, az,  0, 0, 0);
        anx = __builtin_amdgcn_mfma_f32_16x16x32_bf16(WNx[0], XN0, anx, 0, 0, 0);
        anx = __builtin_amdgcn_mfma_f32_16x16x32_bf16(WNx[1], XN1, anx, 0, 0, 0);

        const bool valid = (t < len);
#pragma unroll
        for (int r = 0; r < 4; ++r) {
            const float rg = __builtin_amdgcn_rcpf(1.f + __expf(-ar[r]));
            const float zg = __builtin_amdgcn_rcpf(1.f + __expf(-az[r]));
            const float nv = anx[r] + rg * anh[r];
            const float ng = 1.f - 2.f * __builtin_amdgcn_rcpf(1.f + __expf(2.f * nv));
            const float hnew = (1.f - zg) * ng + zg * hreg[r];
            hreg[r] = valid ? hnew : hreg[r];
        }
        {   // ys store (drain-free) + bf16 h for next step
            float4 o;
            o.x = hreg[0]; o.y = hreg[1]; o.z = hreg[2]; o.w = hreg[3];
            *(float4*)&ys[((size_t)t * BB + b0 + col) * HH + g0] = o;
            int2 pk;
            pk.x = pack2bf(hreg[0], hreg[1]);
            pk.y = pack2bf(hreg[2], hreg[3]);
            *(int2*)&hbf[p ^ 1][col * 136 + g0] = pk;
        }
        if (t + 1 < SS)
            *(int*)&xbf[p ^ 1][srow * 72 + scol] =
                pack2bf(fmaf(xv.x, ax0, cx0), fmaf(xv.y, ax1, cx1));

        sync_lds();
        p ^= 1;
    }

    {
        float4 hl;
        hl.x = hreg[0]; hl.y = hreg[1]; hl.z = hreg[2]; hl.w = hreg[3];
        *(float4*)&hlast[(size_t)(b0 + col) * HH + g0] = hl;
    }
}

// ---------------------------------------------------------------------------
// K4: 3-layer MLP, in-place on d_out. 512 blocks x 512 threads; 16 tiles of
// 16 tokens per block, 3-stage pipeline (L1 tile i / L2 i-1 / L3 i-2) with
// ONE lgkm-only barrier per step; next tile's y/xd prefetched in registers.
// Weights VGPR-resident (13 frags = 52 VGPR).
// ---------------------------------------------------------------------------
__global__ __launch_bounds__(512, 2) void mlp_kernel(
    const float* __restrict__ xd, const int* __restrict__ lengths,
    const float* __restrict__ W1, const float* __restrict__ b1v,
    const float* __restrict__ W2, const float* __restrict__ b2v,
    const float* __restrict__ W3, const float* __restrict__ b3v,
    const float* __restrict__ der, float* io)
{
    __shared__ __align__(16) short z0[2][16 * 168];
    __shared__ __align__(16) short d1b[2][16 * 136];
    __shared__ __align__(16) short d2b[2][16 * 136];

    const int tid  = threadIdx.x;
    const int w    = tid >> 6;
    const int l    = tid & 63;
    const int col  = l & 15;
    const int quad = l >> 4;
    const int ur   = 16 * w + col;
    const int g0   = 16 * w + quad * 4;

    short8 F1[5], F2[4], F3[4];
#pragma unroll
    for (int ks = 0; ks < 5; ++ks)
        F1[ks] = load8bf(&W1[(size_t)ur * 160 + ks * 32 + quad * 8]);
#pragma unroll
    for (int ks = 0; ks < 4; ++ks) {
        const int ko = ks * 32 + quad * 8;
        F2[ks] = load8bf(&W2[(size_t)ur * HH + ko]);
        F3[ks] = load8bf(&W3[(size_t)ur * HH + ko]);
    }
    float bb1_[4], bb2_[4], bb3_[4];
#pragma unroll
    for (int r = 0; r < 4; ++r) {
        bb1_[r] = b1v[g0 + r]; bb2_[r] = b2v[g0 + r]; bb3_[r] = b3v[g0 + r];
    }

    // staging maps: y = 512 thr x float4 (16x128); xd = 256 thr x float2 (16x32)
    const int yrow = tid >> 5, yc = (tid & 31) * 4;
    const int drow = tid >> 4, dcol = (tid & 15) * 2;
    float ad0 = 0.f, ad1 = 0.f, cd0 = 0.f, cd1 = 0.f;
    if (tid < 256) {
        ad0 = der[128 + dcol]; ad1 = der[128 + dcol + 1];
        cd0 = der[160 + dcol]; cd1 = der[160 + dcol + 1];
    }

    const int tile0 = blockIdx.x * 16;

    {   // pre-stage tile 0
        const size_t tok0 = (size_t)tile0 * 16;
        const float4 yv = *(const float4*)&io[(tok0 + yrow) * HH + yc];
        int2 pk;
        pk.x = pack2bf(yv.x, yv.y);
        pk.y = pack2bf(yv.z, yv.w);
        *(int2*)&z0[0][yrow * 168 + yc] = pk;
        if (tid < 256) {
            const float2 dv = *(const float2*)&xd[(tok0 + drow) * DD + dcol];
            *(int*)&z0[0][drow * 168 + HH + dcol] =
                pack2bf(fmaf(dv.x, ad0, cd0), fmaf(dv.y, ad1, cd1));
        }
    }
    sync_lds();

    int p = 0;
    for (int it = 0; it <= 17; ++it) {
        // prefetch tile it+1 into registers
        float4 yv; float2 dv;
        const int nt = it + 1;
        if (nt <= 15) {
            const size_t tok0n = (size_t)(tile0 + nt) * 16;
            yv = *(const float4*)&io[(tok0n + yrow) * HH + yc];
            if (tid < 256) dv = *(const float2*)&xd[(tok0n + drow) * DD + dcol];
        }

        // L1 (tile it): z0[p] -> d1b[p^1]
        f32x4 a1 = {bb1_[0], bb1_[1], bb1_[2], bb1_[3]};
#pragma unroll
        for (int ks = 0; ks < 5; ++ks)
            a1 = __builtin_amdgcn_mfma_f32_16x16x32_bf16(
                F1[ks], *(const short8*)&z0[p][col * 168 + ks * 32 + quad * 8], a1, 0, 0, 0);
        {
            int2 pk;
            pk.x = pack2bf(fmaxf(a1[0], 0.f), fmaxf(a1[1], 0.f));
            pk.y = pack2bf(fmaxf(a1[2], 0.f), fmaxf(a1[3], 0.f));
            *(int2*)&d1b[p ^ 1][col * 136 + g0] = pk;
        }

        // L2 (tile it-1): d1b[p] -> d2b[p^1]
        f32x4 a2 = {bb2_[0], bb2_[1], bb2_[2], bb2_[3]};
#pragma unroll
        for (int ks = 0; ks < 4; ++ks)
            a2 = __builtin_amdgcn_mfma_f32_16x16x32_bf16(
                F2[ks], *(const short8*)&d1b[p][col * 136 + ks * 32 + quad * 8], a2, 0, 0, 0);
        {
            int2 pk;
            pk.x = pack2bf(fmaxf(a2[0], 0.f), fmaxf(a2[1], 0.f));
            pk.y = pack2bf(fmaxf(a2[2], 0.f), fmaxf(a2[3], 0.f));
            *(int2*)&d2b[p ^ 1][col * 136 + g0] = pk;
        }

        // L3 (tile it-2): d2b[p] -> out (drain-free store)
        f32x4 a3 = {bb3_[0], bb3_[1], bb3_[2], bb3_[3]};
#pragma unroll
        for (int ks = 0; ks < 4; ++ks)
            a3 = __builtin_amdgcn_mfma_f32_16x16x32_bf16(
                F3[ks], *(const short8*)&d2b[p][col * 136 + ks * 32 + quad * 8], a3, 0, 0, 0);
        if (it >= 2) {
            const int tok0 = (tile0 + it - 2) * 16;
            const int tI = tok0 >> 9;
            const int bI = tok0 & (BB - 1);
            const bool v = tI < lengths[bI + col];
            float4 o;
            o.x = v ? fmaxf(a3[0], 0.f) : 0.f;
            o.y = v ? fmaxf(a3[1], 0.f) : 0.f;
            o.z = v ? fmaxf(a3[2], 0.f) : 0.f;
            o.w = v ? fmaxf(a3[3], 0.f) : 0.f;
            *(float4*)&io[((size_t)tok0 + col) * HH + g0] = o;
        }

        // commit prefetched tile it+1 to z0[p^1]
        if (nt <= 15) {
            int2 pk;
            pk.x = pack2bf(yv.x, yv.y);
            pk.y = pack2bf(yv.z, yv.w);
            *(int2*)&z0[p ^ 1][yrow * 168 + yc] = pk;
            if (tid < 256)
                *(int*)&z0[p ^ 1][drow * 168 + HH + dcol] =
                    pack2bf(fmaf(dv.x, ad0, cd0), fmaf(dv.y, ad1, cd1));
        }
        sync_lds();
        p ^= 1;
    }
}

// ---------------------------------------------------------------------------
extern "C" void kernel_launch(void* const* d_in, const int* in_sizes, int n_in,
                              void* d_out, int out_size, void* d_ws, size_t ws_size,
                              hipStream_t stream)
{
    (void)in_sizes; (void)n_in; (void)out_size; (void)ws_size;
    const float* x     = (const float*)d_in[0];
    const float* xd    = (const float*)d_in[1];
    const int*   lens  = (const int*)d_in[2];
    const float* bn_g  = (const float*)d_in[3];
    const float* bn_b  = (const float*)d_in[4];
    const float* bnd_g = (const float*)d_in[5];
    const float* bnd_b = (const float*)d_in[6];
    const float* Wih   = (const float*)d_in[7];
    const float* Whh   = (const float*)d_in[8];
    const float* bih   = (const float*)d_in[9];
    const float* bhh   = (const float*)d_in[10];
    // d_in[11], d_in[12]: attn_W, attn_b — softmax over size-1 axis == identity
    const float* W1    = (const float*)d_in[13];
    const float* b1    = (const float*)d_in[14];
    const float* W2    = (const float*)d_in[15];
    const float* b2    = (const float*)d_in[16];
    const float* W3    = (const float*)d_in[17];
    const float* b3    = (const float*)d_in[18];

    float* out   = (float*)d_out;
    float* hlast = out + (size_t)SS * BB * HH;

    double*   acc     = (double*)d_ws;                     // 192 doubles
    unsigned* counter = (unsigned*)((char*)d_ws + 1536);   // ticket
    float*    der     = (float*)((char*)d_ws + 2048);      // 192 floats

    (void)hipMemsetAsync(d_ws, 0, 2048, stream);

    stats_kernel<<<384, 256, 0, stream>>>(x, xd, lens, acc, counter,
                                          bn_g, bn_b, bnd_g, bnd_b, der);

    gru_kernel<<<BB / 16, 512, 0, stream>>>(x, lens, Wih, Whh, bih, bhh, der,
                                            out, hlast);

    mlp_kernel<<<512, 512, 0, stream>>>(xd, lens, W1, b1, W2, b2, W3, b3,
                                        der, out);
}